// Round 1
// baseline (935.651 us; speedup 1.0000x reference)
//
#include <hip/hip_runtime.h>
#include <cstdint>
#include <cstddef>

// Problem constants
#define TOKENS 2048
#define DM 1024
#define DFF 2048
#define HC 4096   // 2*DFF
#define NAG 4
#define NBG 4
#define NE 16

typedef __bf16 bf16x8 __attribute__((ext_vector_type(8)));
typedef float floatx4 __attribute__((ext_vector_type(4)));

static __device__ __forceinline__ unsigned short f2bf(float f) {
    union { float f; unsigned int u; } v; v.f = f;
    unsigned int r = v.u + 0x7fffu + ((v.u >> 16) & 1u);  // round-to-nearest-even
    return (unsigned short)(r >> 16);
}

// ---------------- gating: logits (fp64 accum), softmax, argmax, aux stats ----
__global__ __launch_bounds__(256) void moe_gating(
    const float* __restrict__ x, const float* __restrict__ Wga, const float* __restrict__ bga,
    const float* __restrict__ Wgb, const float* __restrict__ bgb,
    int* __restrict__ e_idx, int* __restrict__ countE,
    float* __restrict__ sumPA, float* __restrict__ sumPB,
    int* __restrict__ cntA, int* __restrict__ cntB)
{
    int wv = threadIdx.x >> 6, lane = threadIdx.x & 63;
    int t = blockIdx.x * 4 + wv;
    const float* xr = x + (size_t)t * DM;
    double aA[4] = {0.,0.,0.,0.}, aB[4] = {0.,0.,0.,0.};
    for (int k = lane; k < DM; k += 64) {
        double xv = (double)xr[k];
        float4 wa = *(const float4*)(Wga + k * 4);
        float4 wb = *(const float4*)(Wgb + k * 4);
        aA[0] += xv * wa.x; aA[1] += xv * wa.y; aA[2] += xv * wa.z; aA[3] += xv * wa.w;
        aB[0] += xv * wb.x; aB[1] += xv * wb.y; aB[2] += xv * wb.z; aB[3] += xv * wb.w;
    }
    #pragma unroll
    for (int off = 32; off >= 1; off >>= 1) {
        #pragma unroll
        for (int j = 0; j < 4; ++j) {
            aA[j] += __shfl_xor(aA[j], off);
            aB[j] += __shfl_xor(aB[j], off);
        }
    }
    if (lane == 0) {
        double lA[4], lB[4];
        #pragma unroll
        for (int j = 0; j < 4; ++j) {
            lA[j] = aA[j] + (double)bga[j];
            lB[j] = aB[j] + (double)bgb[j];
        }
        int ia = 0, ib = 0;
        #pragma unroll
        for (int j = 1; j < 4; ++j) {
            if (lA[j] > lA[ia]) ia = j;     // strict > : first max, matches argmax
            if (lB[j] > lB[ib]) ib = j;
        }
        double sA = 0., sB = 0., pA[4], pB[4];
        #pragma unroll
        for (int j = 0; j < 4; ++j) {
            pA[j] = exp(lA[j] - lA[ia]); sA += pA[j];
            pB[j] = exp(lB[j] - lB[ib]); sB += pB[j];
        }
        #pragma unroll
        for (int j = 0; j < 4; ++j) {
            atomicAdd(&sumPA[j], (float)(pA[j] / sA));
            atomicAdd(&sumPB[j], (float)(pB[j] / sB));
        }
        atomicAdd(&cntA[ia], 1);
        atomicAdd(&cntB[ib], 1);
        int e = ia * NBG + ib;
        e_idx[t] = e;
        atomicAdd(&countE[e], 1);
    }
}

// ---------------- prefix-sum over expert counts + aux scalar ----------------
__global__ void moe_prefix_aux(const int* __restrict__ countE, int* __restrict__ offsets,
                               const float* __restrict__ sumPA, const float* __restrict__ sumPB,
                               const int* __restrict__ cntA, const int* __restrict__ cntB,
                               float* __restrict__ aux_out)
{
    if (threadIdx.x != 0 || blockIdx.x != 0) return;
    int acc = 0;
    for (int e = 0; e < NE; ++e) { offsets[e] = acc; acc += countE[e]; }
    offsets[NE] = acc;
    float invT = 1.0f / (float)TOKENS;
    float auxA = 0.f, auxB = 0.f;
    for (int j = 0; j < 4; ++j) {
        auxA += (sumPA[j] * invT) * ((float)cntA[j] * invT);
        auxB += (sumPB[j] * invT) * ((float)cntB[j] * invT);
    }
    aux_out[0] = (float)NAG * auxA + (float)NBG * auxB;
}

// ---------------- assign each token a compact slot within its expert --------
__global__ __launch_bounds__(256) void moe_slot(const int* __restrict__ e_idx,
                                                const int* __restrict__ offsets,
                                                int* __restrict__ cursor, int* __restrict__ perm)
{
    int t = blockIdx.x * 256 + threadIdx.x;
    int e = e_idx[t];
    int s = offsets[e] + atomicAdd(&cursor[e], 1);
    perm[s] = t;
}

// ---------------- gather x rows into expert-sorted bf16 buffer --------------
__global__ __launch_bounds__(256) void moe_gather(const float* __restrict__ x,
                                                  const int* __restrict__ perm,
                                                  unsigned short* __restrict__ Xg)
{
    int s = blockIdx.x;
    int t = perm[s];
    int i = threadIdx.x * 4;
    float4 v = *(const float4*)(x + (size_t)t * DM + i);
    ushort4 o;
    o.x = f2bf(v.x); o.y = f2bf(v.y); o.z = f2bf(v.z); o.w = f2bf(v.w);
    *(ushort4*)(Xg + (size_t)s * DM + i) = o;
}

// ---------------- GEMM1: h = Xg @ W1[e] (+b1), act = a * silu(g) ------------
// grid (DFF/64, NE). block 256 = 4 waves. Each block: 64 act-cols (paired a/g),
// M-loop over expert tokens in tiles of 64. BK=32, mfma 16x16x32 bf16.
__global__ __launch_bounds__(256) void moe_ffn1(
    const unsigned short* __restrict__ Xg, const float* __restrict__ W1,
    const float* __restrict__ b1, const int* __restrict__ countE,
    const int* __restrict__ offsets, unsigned short* __restrict__ actbuf)
{
    int e = blockIdx.y;
    int cnt = countE[e];
    if (cnt == 0) return;
    int base = offsets[e];
    int n0 = blockIdx.x * 64;
    __shared__ __align__(16) unsigned short Xs[64 * 40];   // [row][k], stride 40
    __shared__ __align__(16) unsigned short Ws[128 * 40];  // [tilecol][k], stride 40
    int tid = threadIdx.x, wv = tid >> 6, lane = tid & 63;
    int quad = lane >> 4, l15 = lane & 15;
    const float* W1e = W1 + (size_t)e * DM * HC;

    int col = n0 + wv * 16 + l15;             // act column owned by this lane
    float ba = b1[e * HC + col];
    float bg = b1[e * HC + DFF + col];

    for (int m0 = 0; m0 < cnt; m0 += 64) {
        floatx4 acc[4][2];
        #pragma unroll
        for (int i = 0; i < 4; ++i) {
            acc[i][0] = floatx4{0.f, 0.f, 0.f, 0.f};
            acc[i][1] = floatx4{0.f, 0.f, 0.f, 0.f};
        }
        for (int k0 = 0; k0 < DM; k0 += 32) {
            __syncthreads();
            {   // stage X tile: 64 rows x 32 k (bf16, already converted)
                int row = tid >> 2, kc = tid & 3;
                uint4 v = {0u, 0u, 0u, 0u};
                int m = m0 + row;
                if (m < cnt) v = *(const uint4*)(Xg + (size_t)(base + m) * DM + k0 + kc * 8);
                *(uint4*)(Xs + row * 40 + kc * 8) = v;
            }
            // stage W tile: 128 tile-cols (64 a-cols + 64 g-cols, interleaved
            // per-wave) x 32 k, fp32 -> bf16, transposed into LDS
            #pragma unroll
            for (int p = 0; p < 2; ++p) {
                int task = tid + p * 256;
                int c = task & 127, kc = task >> 7;
                int w = c >> 5, within = c & 31;
                int gcol = (within < 16) ? (n0 + w * 16 + within)
                                         : (DFF + n0 + w * 16 + (within - 16));
                const float* src = W1e + (size_t)(k0 + kc * 8) * HC + gcol;
                unsigned short tmp[8];
                #pragma unroll
                for (int i = 0; i < 8; ++i) tmp[i] = f2bf(src[(size_t)i * HC]);
                *(uint4*)(Ws + c * 40 + kc * 8) = *(const uint4*)tmp;
            }
            __syncthreads();
            bf16x8 af[4], bfr[2];
            #pragma unroll
            for (int i = 0; i < 4; ++i)
                af[i] = *(const bf16x8*)(Xs + (i * 16 + l15) * 40 + quad * 8);
            #pragma unroll
            for (int j = 0; j < 2; ++j)
                bfr[j] = *(const bf16x8*)(Ws + (wv * 32 + j * 16 + l15) * 40 + quad * 8);
            #pragma unroll
            for (int i = 0; i < 4; ++i) {
                acc[i][0] = __builtin_amdgcn_mfma_f32_16x16x32_bf16(af[i], bfr[0], acc[i][0], 0, 0, 0);
                acc[i][1] = __builtin_amdgcn_mfma_f32_16x16x32_bf16(af[i], bfr[1], acc[i][1], 0, 0, 0);
            }
        }
        // epilogue: act = (a+ba) * silu(g+bg), store bf16
        #pragma unroll
        for (int i = 0; i < 4; ++i) {
            #pragma unroll
            for (int r = 0; r < 4; ++r) {
                int mr = m0 + i * 16 + quad * 4 + r;
                if (mr < cnt) {
                    float a = acc[i][0][r] + ba;
                    float g = acc[i][1][r] + bg;
                    float sg = 1.0f / (1.0f + __expf(-g));
                    actbuf[(size_t)(base + mr) * DFF + col] = f2bf(a * (g * sg));
                }
            }
        }
    }
}

// ---------------- GEMM2: y = act @ W2[e] + b2, scatter rows via perm --------
// grid (DM/64, NE). block 256 = 4 waves, each wave 64x16 of the 64x64 tile.
__global__ __launch_bounds__(256) void moe_ffn2(
    const unsigned short* __restrict__ actbuf, const float* __restrict__ W2,
    const float* __restrict__ b2, const int* __restrict__ countE,
    const int* __restrict__ offsets, const int* __restrict__ perm,
    float* __restrict__ out)
{
    int e = blockIdx.y;
    int cnt = countE[e];
    if (cnt == 0) return;
    int base = offsets[e];
    int n0 = blockIdx.x * 64;
    __shared__ __align__(16) unsigned short As[64 * 40];
    __shared__ __align__(16) unsigned short Bs[64 * 40];
    int tid = threadIdx.x, wv = tid >> 6, lane = tid & 63;
    int quad = lane >> 4, l15 = lane & 15;
    const float* W2e = W2 + (size_t)e * DFF * DM;
    int col = n0 + wv * 16 + l15;
    float bias = b2[e * DM + col];

    for (int m0 = 0; m0 < cnt; m0 += 64) {
        floatx4 acc[4];
        #pragma unroll
        for (int i = 0; i < 4; ++i) acc[i] = floatx4{0.f, 0.f, 0.f, 0.f};
        for (int k0 = 0; k0 < DFF; k0 += 32) {
            __syncthreads();
            {   // stage act tile (bf16)
                int row = tid >> 2, kc = tid & 3;
                uint4 v = {0u, 0u, 0u, 0u};
                int m = m0 + row;
                if (m < cnt) v = *(const uint4*)(actbuf + (size_t)(base + m) * DFF + k0 + kc * 8);
                *(uint4*)(As + row * 40 + kc * 8) = v;
            }
            {   // stage W2 tile: 64 cols x 32 k, fp32 -> bf16, transposed
                int c = tid & 63, kc = tid >> 6;
                const float* src = W2e + (size_t)(k0 + kc * 8) * DM + n0 + c;
                unsigned short tmp[8];
                #pragma unroll
                for (int i = 0; i < 8; ++i) tmp[i] = f2bf(src[(size_t)i * DM]);
                *(uint4*)(Bs + c * 40 + kc * 8) = *(const uint4*)tmp;
            }
            __syncthreads();
            bf16x8 af[4];
            #pragma unroll
            for (int i = 0; i < 4; ++i)
                af[i] = *(const bf16x8*)(As + (i * 16 + l15) * 40 + quad * 8);
            bf16x8 bfr = *(const bf16x8*)(Bs + (wv * 16 + l15) * 40 + quad * 8);
            #pragma unroll
            for (int i = 0; i < 4; ++i)
                acc[i] = __builtin_amdgcn_mfma_f32_16x16x32_bf16(af[i], bfr, acc[i], 0, 0, 0);
        }
        #pragma unroll
        for (int i = 0; i < 4; ++i) {
            #pragma unroll
            for (int r = 0; r < 4; ++r) {
                int mr = m0 + i * 16 + quad * 4 + r;
                if (mr < cnt) {
                    int t = perm[base + mr];
                    out[(size_t)t * DM + col] = acc[i][r] + bias;
                }
            }
        }
    }
}

extern "C" void kernel_launch(void* const* d_in, const int* in_sizes, int n_in,
                              void* d_out, int out_size, void* d_ws, size_t ws_size,
                              hipStream_t stream)
{
    (void)in_sizes; (void)n_in; (void)out_size; (void)ws_size;
    const float* x   = (const float*)d_in[0];
    const float* W1  = (const float*)d_in[1];
    const float* b1  = (const float*)d_in[2];
    const float* W2  = (const float*)d_in[3];
    const float* b2  = (const float*)d_in[4];
    const float* Wga = (const float*)d_in[5];
    const float* bga = (const float*)d_in[6];
    const float* Wgb = (const float*)d_in[7];
    const float* bgb = (const float*)d_in[8];
    float* out = (float*)d_out;

    // workspace layout (needs 16 MiB):
    //   [0,64)    countE[16]      [64,128)  cursor[16]
    //   [128,144) sumPA[4]        [144,160) sumPB[4]
    //   [160,176) cntA[4]         [176,192) cntB[4]
    //   [256,...) offsets[17]
    //   [512,...) e_idx[2048]     [+8192)   perm[2048]
    //   [32768)   Xg bf16 [2048][1024]      (4 MiB)
    //   [8 MiB)   actbuf bf16 [2048][2048]  (8 MiB)
    char* ws = (char*)d_ws;
    int*   countE  = (int*)(ws + 0);
    int*   cursor  = (int*)(ws + 64);
    float* sumPA   = (float*)(ws + 128);
    float* sumPB   = (float*)(ws + 144);
    int*   cntA    = (int*)(ws + 160);
    int*   cntB    = (int*)(ws + 176);
    int*   offsets = (int*)(ws + 256);
    int*   e_idx   = (int*)(ws + 512);
    int*   perm    = (int*)(ws + 512 + 4 * TOKENS);
    unsigned short* Xg     = (unsigned short*)(ws + 32768);
    unsigned short* actbuf = (unsigned short*)(ws + (size_t)8 * 1024 * 1024);

    hipMemsetAsync(ws, 0, 256, stream);
    moe_gating<<<TOKENS / 4, 256, 0, stream>>>(x, Wga, bga, Wgb, bgb,
                                               e_idx, countE, sumPA, sumPB, cntA, cntB);
    moe_prefix_aux<<<1, 64, 0, stream>>>(countE, offsets, sumPA, sumPB, cntA, cntB,
                                         out + (size_t)TOKENS * DM);
    moe_slot<<<TOKENS / 256, 256, 0, stream>>>(e_idx, offsets, cursor, perm);
    moe_gather<<<TOKENS, 256, 0, stream>>>(x, perm, Xg);
    moe_ffn1<<<dim3(DFF / 64, NE), 256, 0, stream>>>(Xg, W1, b1, countE, offsets, actbuf);
    moe_ffn2<<<dim3(DM / 64, NE), 256, 0, stream>>>(actbuf, W2, b2, countE, offsets, perm, out);
}

// Round 2
// 579.410 us; speedup vs baseline: 1.6148x; 1.6148x over previous
//
#include <hip/hip_runtime.h>
#include <cstdint>
#include <cstddef>

// Problem constants
#define TOKENS 2048
#define DM 1024
#define DFF 2048
#define HC 4096   // 2*DFF
#define NE 16
#define BM 128    // M-tile for both GEMMs

typedef __bf16 bf16x8 __attribute__((ext_vector_type(8)));
typedef float floatx4 __attribute__((ext_vector_type(4)));

static __device__ __forceinline__ unsigned short f2bf(float f) {
    union { float f; unsigned int u; } v; v.f = f;
    unsigned int r = v.u + 0x7fffu + ((v.u >> 16) & 1u);  // RNE
    return (unsigned short)(r >> 16);
}

union BF8 { bf16x8 v; unsigned short u[8]; };

// ---------------- gating: logits (fp64 accum), softmax, argmax — NO atomics --
__global__ __launch_bounds__(256) void moe_gating(
    const float* __restrict__ x, const float* __restrict__ Wga, const float* __restrict__ bga,
    const float* __restrict__ Wgb, const float* __restrict__ bgb,
    float* __restrict__ probsA, float* __restrict__ probsB, int* __restrict__ e_idx)
{
    int wv = threadIdx.x >> 6, lane = threadIdx.x & 63;
    int t = blockIdx.x * 4 + wv;
    const float* xr = x + (size_t)t * DM;
    double aA[4] = {0.,0.,0.,0.}, aB[4] = {0.,0.,0.,0.};
    for (int k = lane; k < DM; k += 64) {
        double xv = (double)xr[k];
        float4 wa = *(const float4*)(Wga + k * 4);
        float4 wb = *(const float4*)(Wgb + k * 4);
        aA[0] += xv * wa.x; aA[1] += xv * wa.y; aA[2] += xv * wa.z; aA[3] += xv * wa.w;
        aB[0] += xv * wb.x; aB[1] += xv * wb.y; aB[2] += xv * wb.z; aB[3] += xv * wb.w;
    }
    #pragma unroll
    for (int off = 32; off >= 1; off >>= 1) {
        #pragma unroll
        for (int j = 0; j < 4; ++j) {
            aA[j] += __shfl_xor(aA[j], off);
            aB[j] += __shfl_xor(aB[j], off);
        }
    }
    if (lane == 0) {
        double lA[4], lB[4];
        #pragma unroll
        for (int j = 0; j < 4; ++j) {
            lA[j] = aA[j] + (double)bga[j];
            lB[j] = aB[j] + (double)bgb[j];
        }
        int ia = 0, ib = 0;
        #pragma unroll
        for (int j = 1; j < 4; ++j) {
            if (lA[j] > lA[ia]) ia = j;   // first-max, matches np.argmax
            if (lB[j] > lB[ib]) ib = j;
        }
        double sA = 0., sB = 0., pA[4], pB[4];
        #pragma unroll
        for (int j = 0; j < 4; ++j) {
            pA[j] = exp(lA[j] - lA[ia]); sA += pA[j];
            pB[j] = exp(lB[j] - lB[ib]); sB += pB[j];
        }
        float4 oa, ob;
        oa.x = (float)(pA[0]/sA); oa.y = (float)(pA[1]/sA);
        oa.z = (float)(pA[2]/sA); oa.w = (float)(pA[3]/sA);
        ob.x = (float)(pB[0]/sB); ob.y = (float)(pB[1]/sB);
        ob.z = (float)(pB[2]/sB); ob.w = (float)(pB[3]/sB);
        *(float4*)(probsA + t * 4) = oa;
        *(float4*)(probsB + t * 4) = ob;
        e_idx[t] = ia * 4 + ib;
    }
}

// ---------------- single-block stats: sums, counts, offsets, aux ------------
__global__ __launch_bounds__(256) void moe_stats(
    const float* __restrict__ probsA, const float* __restrict__ probsB,
    const int* __restrict__ e_idx,
    int* __restrict__ countE, int* __restrict__ offsets, float* __restrict__ aux_out)
{
    __shared__ float sA[4], sB[4];
    __shared__ int cA[4], cB[4], cE[16];
    int tid = threadIdx.x;
    if (tid < 4) { sA[tid] = 0.f; sB[tid] = 0.f; cA[tid] = 0; cB[tid] = 0; }
    if (tid < 16) cE[tid] = 0;
    __syncthreads();
    float lA[4] = {0,0,0,0}, lB[4] = {0,0,0,0};
    for (int t = tid; t < TOKENS; t += 256) {
        float4 pa = *(const float4*)(probsA + t * 4);
        float4 pb = *(const float4*)(probsB + t * 4);
        lA[0] += pa.x; lA[1] += pa.y; lA[2] += pa.z; lA[3] += pa.w;
        lB[0] += pb.x; lB[1] += pb.y; lB[2] += pb.z; lB[3] += pb.w;
        int e = e_idx[t];
        atomicAdd(&cE[e], 1);
        atomicAdd(&cA[e >> 2], 1);
        atomicAdd(&cB[e & 3], 1);
    }
    #pragma unroll
    for (int j = 0; j < 4; ++j) {
        atomicAdd(&sA[j], lA[j]);
        atomicAdd(&sB[j], lB[j]);
    }
    __syncthreads();
    if (tid == 0) {
        int acc = 0;
        for (int e = 0; e < NE; ++e) { offsets[e] = acc; countE[e] = cE[e]; acc += cE[e]; }
        offsets[NE] = acc;
        float invT = 1.0f / (float)TOKENS;
        float auxA = 0.f, auxB = 0.f;
        for (int j = 0; j < 4; ++j) {
            auxA += (sA[j] * invT) * ((float)cA[j] * invT);
            auxB += (sB[j] * invT) * ((float)cB[j] * invT);
        }
        aux_out[0] = 4.0f * auxA + 4.0f * auxB;
    }
}

// ---------------- assign each token a compact slot within its expert --------
__global__ __launch_bounds__(256) void moe_slot(const int* __restrict__ e_idx,
                                                const int* __restrict__ offsets,
                                                int* __restrict__ cursor, int* __restrict__ perm)
{
    int t = blockIdx.x * 256 + threadIdx.x;
    int e = e_idx[t];
    int s = offsets[e] + atomicAdd(&cursor[e], 1);
    perm[s] = t;
}

// ---------------- gather x rows into expert-sorted bf16 buffer --------------
__global__ __launch_bounds__(256) void moe_gather(const float* __restrict__ x,
                                                  const int* __restrict__ perm,
                                                  unsigned short* __restrict__ Xg)
{
    int s = blockIdx.x;
    int t = perm[s];
    int i = threadIdx.x * 4;
    float4 v = *(const float4*)(x + (size_t)t * DM + i);
    ushort4 o;
    o.x = f2bf(v.x); o.y = f2bf(v.y); o.z = f2bf(v.z); o.w = f2bf(v.w);
    *(ushort4*)(Xg + (size_t)s * DM + i) = o;
}

// ---------------- GEMM1: h = Xg @ W1[e] (+b1), act = a * silu(g) ------------
// grid (DFF/64, NE, 2). block 256 = 4 waves. Per block: 64 a-cols + 64 g-cols
// (wave wv owns 16 of each), M-tile 128, BK=32. B-frags loaded DIRECT from
// global fp32 (lane = column, 8 k-strided dwords, coalesced across lanes),
// converted to bf16 in-register. Double-buffered LDS A-tile, one barrier/step,
// B prefetched one step ahead so loads stay in flight across the barrier.
__global__ __launch_bounds__(256) void moe_ffn1(
    const unsigned short* __restrict__ Xg, const float* __restrict__ W1,
    const float* __restrict__ b1, const int* __restrict__ countE,
    const int* __restrict__ offsets, unsigned short* __restrict__ actbuf)
{
    int e = blockIdx.y;
    int cnt = countE[e];
    if (cnt == 0) return;
    int base = offsets[e];
    int n0 = blockIdx.x * 64;
    __shared__ __align__(16) unsigned short Xs[2 * BM * 40];
    int tid = threadIdx.x, wv = tid >> 6, lane = tid & 63;
    int quad = lane >> 4, l15 = lane & 15;
    const float* W1e = W1 + (size_t)e * DM * HC;
    int col = n0 + wv * 16 + l15;
    const float* pa = W1e + col;
    const float* pg = W1e + DFF + col;
    float ba = b1[e * HC + col];
    float bg = b1[e * HC + DFF + col];
    int row = tid >> 2, kc = tid & 3;   // staging assignment (half tile per pass)

    for (int m0 = blockIdx.z * BM; m0 < cnt; m0 += 2 * BM) {
        floatx4 acc[8][2];
        #pragma unroll
        for (int i = 0; i < 8; ++i) {
            acc[i][0] = floatx4{0.f,0.f,0.f,0.f};
            acc[i][1] = floatx4{0.f,0.f,0.f,0.f};
        }
        // stage k-step 0 into buffer 0
        #pragma unroll
        for (int p = 0; p < 2; ++p) {
            int r = row + p * 64;
            uint4 v = {0u,0u,0u,0u};
            int m = m0 + r;
            if (m < cnt) v = *(const uint4*)(Xg + (size_t)(base + m) * DM + kc * 8);
            *(uint4*)(Xs + r * 40 + kc * 8) = v;
        }
        float curA[8], curG[8], nxtA[8], nxtG[8];
        {
            const float* qa = pa + (size_t)(quad * 8) * HC;
            const float* qg = pg + (size_t)(quad * 8) * HC;
            #pragma unroll
            for (int j = 0; j < 8; ++j) { curA[j] = qa[(size_t)j * HC]; curG[j] = qg[(size_t)j * HC]; }
        }
        __syncthreads();
        for (int ks = 0; ks < DM / 32; ++ks) {
            int buf = ks & 1;
            if (ks + 1 < DM / 32) {     // stage next A-tile into other buffer
                int k0n = (ks + 1) * 32;
                #pragma unroll
                for (int p = 0; p < 2; ++p) {
                    int r = row + p * 64;
                    uint4 v = {0u,0u,0u,0u};
                    int m = m0 + r;
                    if (m < cnt) v = *(const uint4*)(Xg + (size_t)(base + m) * DM + k0n + kc * 8);
                    *(uint4*)(Xs + (buf ^ 1) * (BM * 40) + r * 40 + kc * 8) = v;
                }
            }
            bf16x8 af[8];
            #pragma unroll
            for (int i = 0; i < 8; ++i)
                af[i] = *(const bf16x8*)(Xs + buf * (BM * 40) + (i * 16 + l15) * 40 + quad * 8);
            if (ks + 1 < DM / 32) {     // prefetch next B-frags (fp32, in flight)
                const float* qa = pa + (size_t)((ks + 1) * 32 + quad * 8) * HC;
                const float* qg = pg + (size_t)((ks + 1) * 32 + quad * 8) * HC;
                #pragma unroll
                for (int j = 0; j < 8; ++j) { nxtA[j] = qa[(size_t)j * HC]; nxtG[j] = qg[(size_t)j * HC]; }
            }
            BF8 fa, fg;
            #pragma unroll
            for (int j = 0; j < 8; ++j) { fa.u[j] = f2bf(curA[j]); fg.u[j] = f2bf(curG[j]); }
            #pragma unroll
            for (int i = 0; i < 8; ++i) {
                acc[i][0] = __builtin_amdgcn_mfma_f32_16x16x32_bf16(af[i], fa.v, acc[i][0], 0, 0, 0);
                acc[i][1] = __builtin_amdgcn_mfma_f32_16x16x32_bf16(af[i], fg.v, acc[i][1], 0, 0, 0);
            }
            #pragma unroll
            for (int j = 0; j < 8; ++j) { curA[j] = nxtA[j]; curG[j] = nxtG[j]; }
            __syncthreads();
        }
        #pragma unroll
        for (int i = 0; i < 8; ++i) {
            #pragma unroll
            for (int r = 0; r < 4; ++r) {
                int mr = m0 + i * 16 + quad * 4 + r;
                if (mr < cnt) {
                    float a = acc[i][0][r] + ba;
                    float g = acc[i][1][r] + bg;
                    float sg = 1.0f / (1.0f + __expf(-g));
                    actbuf[(size_t)(base + mr) * DFF + col] = f2bf(a * (g * sg));
                }
            }
        }
    }
}

// ---------------- GEMM2: y = act @ W2[e] + b2, scatter rows via perm --------
// grid (DM/64, NE, 2). Same structure: M-tile 128, direct-global B, dbuf LDS A.
__global__ __launch_bounds__(256) void moe_ffn2(
    const unsigned short* __restrict__ actbuf, const float* __restrict__ W2,
    const float* __restrict__ b2, const int* __restrict__ countE,
    const int* __restrict__ offsets, const int* __restrict__ perm,
    float* __restrict__ out)
{
    int e = blockIdx.y;
    int cnt = countE[e];
    if (cnt == 0) return;
    int base = offsets[e];
    int n0 = blockIdx.x * 64;
    __shared__ __align__(16) unsigned short As[2 * BM * 40];
    int tid = threadIdx.x, wv = tid >> 6, lane = tid & 63;
    int quad = lane >> 4, l15 = lane & 15;
    const float* W2e = W2 + (size_t)e * DFF * DM;
    int col = n0 + wv * 16 + l15;
    const float* pb = W2e + col;
    float bias = b2[e * DM + col];
    int row = tid >> 2, kc = tid & 3;

    for (int m0 = blockIdx.z * BM; m0 < cnt; m0 += 2 * BM) {
        floatx4 acc[8];
        #pragma unroll
        for (int i = 0; i < 8; ++i) acc[i] = floatx4{0.f,0.f,0.f,0.f};
        #pragma unroll
        for (int p = 0; p < 2; ++p) {
            int r = row + p * 64;
            uint4 v = {0u,0u,0u,0u};
            int m = m0 + r;
            if (m < cnt) v = *(const uint4*)(actbuf + (size_t)(base + m) * DFF + kc * 8);
            *(uint4*)(As + r * 40 + kc * 8) = v;
        }
        float curB[8], nxtB[8];
        {
            const float* qb = pb + (size_t)(quad * 8) * DM;
            #pragma unroll
            for (int j = 0; j < 8; ++j) curB[j] = qb[(size_t)j * DM];
        }
        __syncthreads();
        for (int ks = 0; ks < DFF / 32; ++ks) {
            int buf = ks & 1;
            if (ks + 1 < DFF / 32) {
                int k0n = (ks + 1) * 32;
                #pragma unroll
                for (int p = 0; p < 2; ++p) {
                    int r = row + p * 64;
                    uint4 v = {0u,0u,0u,0u};
                    int m = m0 + r;
                    if (m < cnt) v = *(const uint4*)(actbuf + (size_t)(base + m) * DFF + k0n + kc * 8);
                    *(uint4*)(As + (buf ^ 1) * (BM * 40) + r * 40 + kc * 8) = v;
                }
            }
            bf16x8 af[8];
            #pragma unroll
            for (int i = 0; i < 8; ++i)
                af[i] = *(const bf16x8*)(As + buf * (BM * 40) + (i * 16 + l15) * 40 + quad * 8);
            if (ks + 1 < DFF / 32) {
                const float* qb = pb + (size_t)((ks + 1) * 32 + quad * 8) * DM;
                #pragma unroll
                for (int j = 0; j < 8; ++j) nxtB[j] = qb[(size_t)j * DM];
            }
            BF8 fb;
            #pragma unroll
            for (int j = 0; j < 8; ++j) fb.u[j] = f2bf(curB[j]);
            #pragma unroll
            for (int i = 0; i < 8; ++i)
                acc[i] = __builtin_amdgcn_mfma_f32_16x16x32_bf16(af[i], fb.v, acc[i], 0, 0, 0);
            #pragma unroll
            for (int j = 0; j < 8; ++j) curB[j] = nxtB[j];
            __syncthreads();
        }
        #pragma unroll
        for (int i = 0; i < 8; ++i) {
            #pragma unroll
            for (int r = 0; r < 4; ++r) {
                int mr = m0 + i * 16 + quad * 4 + r;
                if (mr < cnt) {
                    int t = perm[base + mr];
                    out[(size_t)t * DM + col] = acc[i][r] + bias;
                }
            }
        }
    }
}

extern "C" void kernel_launch(void* const* d_in, const int* in_sizes, int n_in,
                              void* d_out, int out_size, void* d_ws, size_t ws_size,
                              hipStream_t stream)
{
    (void)in_sizes; (void)n_in; (void)out_size; (void)ws_size;
    const float* x   = (const float*)d_in[0];
    const float* W1  = (const float*)d_in[1];
    const float* b1  = (const float*)d_in[2];
    const float* W2  = (const float*)d_in[3];
    const float* b2  = (const float*)d_in[4];
    const float* Wga = (const float*)d_in[5];
    const float* bga = (const float*)d_in[6];
    const float* Wgb = (const float*)d_in[7];
    const float* bgb = (const float*)d_in[8];
    float* out = (float*)d_out;

    // workspace layout (16 MiB):
    //   0      countE[16]     64    cursor[16]     256  offsets[17]
    //   512    e_idx[2048]    8704  perm[2048]
    //   16896  probsA[8192]f  49664 probsB[8192]f
    //   131072 Xg bf16[2048*1024] (4 MiB)
    //   8 MiB  actbuf bf16[2048*2048] (8 MiB)
    char* ws = (char*)d_ws;
    int*   countE  = (int*)(ws + 0);
    int*   cursor  = (int*)(ws + 64);
    int*   offsets = (int*)(ws + 256);
    int*   e_idx   = (int*)(ws + 512);
    int*   perm    = (int*)(ws + 8704);
    float* probsA  = (float*)(ws + 16896);
    float* probsB  = (float*)(ws + 49664);
    unsigned short* Xg     = (unsigned short*)(ws + 131072);
    unsigned short* actbuf = (unsigned short*)(ws + (size_t)8 * 1024 * 1024);

    hipMemsetAsync(ws, 0, 256, stream);   // cursor (and countE, harmlessly)
    moe_gating<<<TOKENS / 4, 256, 0, stream>>>(x, Wga, bga, Wgb, bgb,
                                               probsA, probsB, e_idx);
    moe_stats<<<1, 256, 0, stream>>>(probsA, probsB, e_idx, countE, offsets,
                                     out + (size_t)TOKENS * DM);
    moe_slot<<<TOKENS / 256, 256, 0, stream>>>(e_idx, offsets, cursor, perm);
    moe_gather<<<TOKENS, 256, 0, stream>>>(x, perm, Xg);
    moe_ffn1<<<dim3(DFF / 64, NE, 2), 256, 0, stream>>>(Xg, W1, b1, countE, offsets, actbuf);
    moe_ffn2<<<dim3(DM / 64, NE, 2), 256, 0, stream>>>(actbuf, W2, b2, countE, offsets, perm, out);
}